// Round 8
// baseline (1488.702 us; speedup 1.0000x reference)
//
#include <hip/hip_runtime.h>
#include <hip/hip_bf16.h>

#define N_ 8192
#define T_ 12
#define B_ 2
#define FIN_ 8
#define HID_ 16
#define CGSZ 131072   // one column-group (16 cols) frag block: 256 kb * 64 lanes * 8 elems

typedef short s8v __attribute__((ext_vector_type(8)));
typedef float f4v __attribute__((ext_vector_type(4)));

__device__ __forceinline__ float sigmoidf_(float x){ return 1.f/(1.f + __expf(-x)); }

#define MFMA16(a,b,c) __builtin_amdgcn_mfma_f32_16x16x32_bf16(a,b,c,0,0,0)

// ---------------- prep: L fp32 -> bf16 fragment-major ----------------
// Lp[((rt*256 + kb)*64 + l)*8 + e] = bf16( L[rt*16 + (l&15)][kb*32 + (l>>4)*8 + e] )
__global__ __launch_bounds__(256) void build_Lp_kernel(const float* __restrict__ L,
                                                       __hip_bfloat16* __restrict__ Lp){
  __shared__ unsigned short tile[16][264];
  const int cb = blockIdx.x;   // 0..31
  const int rt = blockIdx.y;   // 0..511
  const int tid = threadIdx.x;
  #pragma unroll
  for (int i = 0; i < 4; ++i){
    int flat = i*256 + tid;
    int r  = flat >> 6;
    int c4 = flat & 63;
    float4 v = *(const float4*)(L + (long)(rt*16 + r)*N_ + cb*256 + c4*4);
    tile[r][c4*4+0] = __bfloat16_as_ushort(__float2bfloat16(v.x));
    tile[r][c4*4+1] = __bfloat16_as_ushort(__float2bfloat16(v.y));
    tile[r][c4*4+2] = __bfloat16_as_ushort(__float2bfloat16(v.z));
    tile[r][c4*4+3] = __bfloat16_as_ushort(__float2bfloat16(v.w));
  }
  __syncthreads();
  #pragma unroll
  for (int j = 0; j < 2; ++j){
    int flat = j*256 + tid;
    int kbl = flat >> 6;
    int l   = flat & 63;
    int lid = l & 15, g = l >> 4;
    uint4 frag = *(const uint4*)&tile[lid][kbl*32 + g*8];
    *(uint4*)(Lp + (((long)rt*256 + cb*8 + kbl)*64 + l)*8) = frag;
  }
}

// ---------------- prep: X (all t) and h0 -> bf16 frag-major (merged) ----------------
__global__ __launch_bounds__(256) void pack_xh_kernel(const float* __restrict__ X,
                                                      const float* __restrict__ H,
                                                      __hip_bfloat16* __restrict__ XTf,
                                                      __hip_bfloat16* __restrict__ hTf){
  if (blockIdx.x < 768){
    const int t = blockIdx.x >> 6;
    int flat = (blockIdx.x & 63)*256 + threadIdx.x;   // 0..16383
    int l = flat & 63, kb = flat >> 6;
    int lid = l & 15, g = l >> 4;
    int b = lid >> 3, f = lid & 7;
    int n0 = kb*32 + g*8;
    unsigned short u[8];
    #pragma unroll
    for (int e = 0; e < 8; ++e)
      u[e] = __bfloat16_as_ushort(__float2bfloat16(
          X[(((long)(b*T_ + t))*N_ + n0 + e)*FIN_ + f]));
    *(uint4*)(XTf + ((long)t*CGSZ + ((long)kb*64 + l)*8)) = *(uint4*)u;
  } else {
    int flat = (blockIdx.x - 768)*256 + threadIdx.x;  // 0..32767
    int l = flat & 63, kb = (flat >> 6) & 255, b = flat >> 14;
    int lid = l & 15, g = l >> 4;
    int n0 = kb*32 + g*8;
    unsigned short u[8];
    #pragma unroll
    for (int e = 0; e < 8; ++e)
      u[e] = __bfloat16_as_ushort(__float2bfloat16(
          H[((long)b*N_ + n0 + e)*HID_ + lid]));
    *(uint4*)(hTf + ((long)b*CGSZ + ((long)kb*64 + l)*8)) = *(uint4*)u;
  }
}

// ---------------- K-split MFMA pass ----------------
// grid (256, 2): blockIdx.x = 2-row-tile pair, blockIdx.y = ks (K half).
// Wave w covers kb in [ks*128 + w*16, +16). 8 waves, 2 blocks/CU.
// NB=3: B streams are full bf16 frags (pass 1).
// NB=6: B streams are 2x partial bf16 frags; linearity folds the K-split
//       sum into the accumulator (v = L*u0 + L*u1).
// WF: also emit partial bf16 frags (pass-1 output feeding pass 2).
template<int NB, bool WF>
__global__ __launch_bounds__(512, 4) void mm_ks_kernel(
    const __hip_bfloat16* __restrict__ Lp,
    const __hip_bfloat16* __restrict__ B0f, const __hip_bfloat16* __restrict__ B1f,
    const __hip_bfloat16* __restrict__ B2f, const __hip_bfloat16* __restrict__ B3f,
    const __hip_bfloat16* __restrict__ B4f, const __hip_bfloat16* __restrict__ B5f,
    __hip_bfloat16* __restrict__ ypf,   // [2][3][CGSZ] partial frags (WF only)
    float* __restrict__ Fh,             // [2][2][N][16] fp32 partials
    float* __restrict__ Fx)             // [2][2][N][8]
{
  __shared__ float red[8][2][3][64][4];   // 49152 B
  const int tid = threadIdx.x, w = tid >> 6, lane = tid & 63;
  const int blk = blockIdx.x, ks = blockIdx.y;
  const int kb0 = ks*128 + w*16;

  const s8v* A0 = (const s8v*)(const void*)Lp + ((long)(blk*2+0)*256 + kb0)*64 + lane;
  const s8v* A1 = (const s8v*)(const void*)Lp + ((long)(blk*2+1)*256 + kb0)*64 + lane;
  const s8v* P0 = (const s8v*)(const void*)B0f + (long)kb0*64 + lane;
  const s8v* P1 = (const s8v*)(const void*)B1f + (long)kb0*64 + lane;
  const s8v* P2 = (const s8v*)(const void*)B2f + (long)kb0*64 + lane;
  const s8v* P3 = (NB==6) ? (const s8v*)(const void*)B3f + (long)kb0*64 + lane : nullptr;
  const s8v* P4 = (NB==6) ? (const s8v*)(const void*)B4f + (long)kb0*64 + lane : nullptr;
  const s8v* P5 = (NB==6) ? (const s8v*)(const void*)B5f + (long)kb0*64 + lane : nullptr;

  f4v a00={0.f,0.f,0.f,0.f}, a01={0.f,0.f,0.f,0.f}, a02={0.f,0.f,0.f,0.f};
  f4v a10={0.f,0.f,0.f,0.f}, a11={0.f,0.f,0.f,0.f}, a12={0.f,0.f,0.f,0.f};

  if constexpr (NB == 3){
    #pragma unroll 4
    for (int kk = 0; kk < 16; ++kk){
      s8v a0 = A0[(long)kk*64];
      s8v a1 = A1[(long)kk*64];
      s8v b0 = P0[(long)kk*64];
      s8v b1 = P1[(long)kk*64];
      s8v b2 = P2[(long)kk*64];
      a00 = MFMA16(a0,b0,a00); a01 = MFMA16(a0,b1,a01); a02 = MFMA16(a0,b2,a02);
      a10 = MFMA16(a1,b0,a10); a11 = MFMA16(a1,b1,a11); a12 = MFMA16(a1,b2,a12);
    }
  } else {
    #pragma unroll 2
    for (int kk = 0; kk < 16; ++kk){
      s8v a0 = A0[(long)kk*64];
      s8v a1 = A1[(long)kk*64];
      s8v b0 = P0[(long)kk*64];
      s8v b1 = P1[(long)kk*64];
      s8v b2 = P2[(long)kk*64];
      s8v b3 = P3[(long)kk*64];
      s8v b4 = P4[(long)kk*64];
      s8v b5 = P5[(long)kk*64];
      a00 = MFMA16(a0,b0,a00); a01 = MFMA16(a0,b1,a01); a02 = MFMA16(a0,b2,a02);
      a10 = MFMA16(a1,b0,a10); a11 = MFMA16(a1,b1,a11); a12 = MFMA16(a1,b2,a12);
      a00 = MFMA16(a0,b3,a00); a01 = MFMA16(a0,b4,a01); a02 = MFMA16(a0,b5,a02);
      a10 = MFMA16(a1,b3,a10); a11 = MFMA16(a1,b4,a11); a12 = MFMA16(a1,b5,a12);
    }
  }

  *(f4v*)&red[w][0][0][lane][0] = a00;
  *(f4v*)&red[w][0][1][lane][0] = a01;
  *(f4v*)&red[w][0][2][lane][0] = a02;
  *(f4v*)&red[w][1][0][lane][0] = a10;
  *(f4v*)&red[w][1][1][lane][0] = a11;
  *(f4v*)&red[w][1][2][lane][0] = a12;
  __syncthreads();

  for (int v = tid; v < 1536; v += 512){
    int rtl = (v >= 768) ? 1 : 0;
    int rem = v - rtl*768;
    int cgI = rem >> 8, r255 = rem & 255;
    int lid = r255 & 15, r = r255 >> 4;
    int g = r >> 2, j = r & 3;
    float s = 0.f;
    #pragma unroll
    for (int ww = 0; ww < 8; ++ww) s += red[ww][rtl][cgI][g*16 + lid][j];
    int n = blk*32 + rtl*16 + r;
    if (WF){
      long o = (((long)cgI*256 + (n>>5))*64 + ((n>>3)&3)*16 + lid)*8 + (n&7);
      ypf[(long)ks*3*CGSZ + o] = __float2bfloat16(s);
    }
    if (cgI < 2) Fh[((long)(ks*B_ + cgI)*N_ + n)*HID_ + lid] = s;
    else         Fx[((long)(ks*B_ + (lid>>3))*N_ + n)*FIN_ + (lid&7)] = s;
  }
}

// ---------------- per-timestep gate / LSTM pointwise (sums K-partials) ----------------
__global__ __launch_bounds__(256) void gate_kernel(
    const float* __restrict__ X, const float* __restrict__ H0, const float* __restrict__ C0,
    const float* __restrict__ Wx, const float* __restrict__ Wh,
    const float* __restrict__ bx, const float* __restrict__ bh,
    const float* __restrict__ wc, const float* __restrict__ bg,
    const float* __restrict__ u_p, const float* __restrict__ p_p,
    const float* __restrict__ v_p, const float* __restrict__ w_p,
    float* __restrict__ out, float* __restrict__ hs, float* __restrict__ cs,
    __hip_bfloat16* __restrict__ hTf, int t)
{
  int idx = blockIdx.x*256 + threadIdx.x;   // [0, 16384)
  int b = idx >> 13, n = idx & (N_-1);

  const float* xp = X + (((long)(b*T_ + t))*N_ + n)*FIN_;
  const float* hp = (t==0) ? (H0 + ((long)b*N_ + n)*HID_)
                           : (hs + (((long)(t-1)*B_ + b)*N_ + n)*HID_);
  const float* cp = (t==0) ? (C0 + ((long)b*N_ + n)*HID_)
                           : (cs + (((long)(t-1)*B_ + b)*N_ + n)*HID_);
  const float* up0 = u_p + ((long)b*N_ + n)*HID_;
  const float* up1 = up0 + (long)B_*N_*HID_;
  const float* pp0 = p_p + ((long)b*N_ + n)*FIN_;
  const float* pp1 = pp0 + (long)B_*N_*FIN_;
  const float* vp0 = v_p + ((long)b*N_ + n)*HID_;
  const float* vp1 = vp0 + (long)B_*N_*HID_;
  const float* wp0 = w_p + ((long)b*N_ + n)*FIN_;
  const float* wp1 = wp0 + (long)B_*N_*FIN_;

  float x[8], pq[8], wq[8], h[16], u[16], v[16], c[16];
  for (int f=0; f<8;  ++f){ x[f]=xp[f]; pq[f]=pp0[f]+pp1[f]; wq[f]=wp0[f]+wp1[f]; }
  for (int j=0; j<16; ++j){ h[j]=hp[j]; u[j]=up0[j]+up1[j]; v[j]=vp0[j]+vp1[j]; c[j]=cp[j]; }

  const float* Wxt = Wx + (long)t*4*3*FIN_*HID_;
  const float* Wht = Wh + (long)t*4*3*HID_*HID_;
  const float* bxt = bx + t*4*HID_;
  const float* bht = bh + t*4*HID_;
  const float* bgt = bg + t*4*HID_;
  const float* wct = wc + t*3*HID_;

  float hn[16], cn[16];
  for (int hd=0; hd<16; ++hd){
    float pre0 = bxt[0*16+hd] + bht[0*16+hd] + bgt[0*16+hd];
    float pre1 = bxt[1*16+hd] + bht[1*16+hd] + bgt[1*16+hd];
    float pre2 = bxt[2*16+hd] + bht[2*16+hd] + bgt[2*16+hd];
    float pre3 = bxt[3*16+hd] + bht[3*16+hd] + bgt[3*16+hd];
    for (int f=0; f<8; ++f){
      float t0 = x[f], t1 = pq[f], t2 = 2.f*wq[f] - x[f];
      pre0 += t0*Wxt[((0*3+0)*8+f)*16+hd] + t1*Wxt[((0*3+1)*8+f)*16+hd] + t2*Wxt[((0*3+2)*8+f)*16+hd];
      pre1 += t0*Wxt[((1*3+0)*8+f)*16+hd] + t1*Wxt[((1*3+1)*8+f)*16+hd] + t2*Wxt[((1*3+2)*8+f)*16+hd];
      pre2 += t0*Wxt[((2*3+0)*8+f)*16+hd] + t1*Wxt[((2*3+1)*8+f)*16+hd] + t2*Wxt[((2*3+2)*8+f)*16+hd];
      pre3 += t0*Wxt[((3*3+0)*8+f)*16+hd] + t1*Wxt[((3*3+1)*8+f)*16+hd] + t2*Wxt[((3*3+2)*8+f)*16+hd];
    }
    for (int j=0; j<16; ++j){
      float t0 = h[j], t1 = u[j], t2 = 2.f*v[j] - h[j];
      pre0 += t0*Wht[((0*3+0)*16+j)*16+hd] + t1*Wht[((0*3+1)*16+j)*16+hd] + t2*Wht[((0*3+2)*16+j)*16+hd];
      pre1 += t0*Wht[((1*3+0)*16+j)*16+hd] + t1*Wht[((1*3+1)*16+j)*16+hd] + t2*Wht[((1*3+2)*16+j)*16+hd];
      pre2 += t0*Wht[((2*3+0)*16+j)*16+hd] + t1*Wht[((2*3+1)*16+j)*16+hd] + t2*Wht[((2*3+2)*16+j)*16+hd];
      pre3 += t0*Wht[((3*3+0)*16+j)*16+hd] + t1*Wht[((3*3+1)*16+j)*16+hd] + t2*Wht[((3*3+2)*16+j)*16+hd];
    }
    float cc = c[hd];
    float ig = sigmoidf_(pre0 + wct[0*16+hd]*cc);
    float fg = sigmoidf_(pre1 + wct[1*16+hd]*cc);
    float cnew = fg*cc + ig*tanhf(pre2);
    float og = sigmoidf_(pre3 + wct[2*16+hd]*cnew);
    cn[hd] = cnew;
    hn[hd] = og*tanhf(cnew);
  }

  float* hso = hs  + (((long)t*B_ + b)*N_ + n)*HID_;
  float* cso = cs  + (((long)t*B_ + b)*N_ + n)*HID_;
  float* oo  = out + (((long)b*T_ + t)*N_ + n)*HID_;
  const int kb = n >> 5, g = (n >> 3) & 3, e = n & 7;
  #pragma unroll
  for (int j=0; j<16; ++j){
    hso[j] = hn[j]; cso[j] = cn[j]; oo[j] = hn[j];
    hTf[(((long)b*256 + kb)*64 + g*16 + j)*8 + e] = __float2bfloat16(hn[j]);
  }
}

extern "C" void kernel_launch(void* const* d_in, const int* in_sizes, int n_in,
                              void* d_out, int out_size, void* d_ws, size_t ws_size,
                              hipStream_t stream)
{
  const float* X  = (const float*)d_in[0];
  const float* L  = (const float*)d_in[1];
  const float* H  = (const float*)d_in[2];
  const float* C  = (const float*)d_in[3];
  const float* Wx = (const float*)d_in[4];
  const float* Wh = (const float*)d_in[5];
  const float* bx = (const float*)d_in[6];
  const float* bh = (const float*)d_in[7];
  const float* wc = (const float*)d_in[8];
  const float* bg = (const float*)d_in[9];

  float* out = (float*)d_out;
  float* hs  = out + (long)B_*T_*N_*HID_;
  float* cs  = hs  + (long)T_*B_*N_*HID_;

  const size_t NEEDED = 145752064;
  if (ws_size < NEEDED) return;
  char* ws = (char*)d_ws;
  __hip_bfloat16* Lp  = (__hip_bfloat16*)(ws);                   // 128 MiB frag-major L
  __hip_bfloat16* XTf = (__hip_bfloat16*)(ws + 134217728);       // 3 MiB   [12][CGSZ]
  __hip_bfloat16* hTf = (__hip_bfloat16*)(ws + 137363456);       // 512 KiB [2][CGSZ]
  __hip_bfloat16* ypf = (__hip_bfloat16*)(ws + 137887744);       // 1.5 MiB [2][3][CGSZ]
  float* u_p = (float*)(ws + 139460608);                         // 2 MiB   [2][2][N][16]
  float* p_p = (float*)(ws + 141557760);                         // 1 MiB   [2][2][N][8]
  float* v_p = (float*)(ws + 142606336);                         // 2 MiB
  float* w_p = (float*)(ws + 144703488);                         // 1 MiB

  build_Lp_kernel<<<dim3(32,512), 256, 0, stream>>>(L, Lp);
  pack_xh_kernel <<<896, 256, 0, stream>>>(X, H, XTf, hTf);

  for (int t = 0; t < T_; ++t){
    // pass 1: partial [u|p] = L_ks @ [h | x_t] -> partial frags + fp32 partials
    mm_ks_kernel<3,true><<<dim3(256,2), 512, 0, stream>>>(
        Lp, hTf, hTf + CGSZ, XTf + (long)t*CGSZ, nullptr, nullptr, nullptr,
        ypf, u_p, p_p);
    // pass 2: partial [v|w] = L_ks @ (u0+u1 | p0+p1) via MFMA linearity
    mm_ks_kernel<6,false><<<dim3(256,2), 512, 0, stream>>>(
        Lp, ypf, ypf + CGSZ, ypf + 2*CGSZ,
        ypf + 3*CGSZ, ypf + 4*CGSZ, ypf + 5*CGSZ,
        nullptr, v_p, w_p);
    // gates: sum partials + LSTM pointwise + next-step h frags
    gate_kernel<<<64, 256, 0, stream>>>(X, H, C, Wx, Wh, bx, bh, wc, bg,
                                        u_p, p_p, v_p, w_p,
                                        out, hs, cs, hTf, t);
  }
}